// Round 5
// baseline (593.782 us; speedup 1.0000x reference)
//
#include <hip/hip_runtime.h>
#include <hip/hip_bf16.h>
#include <stdint.h>

// ---------------------------------------------------------------------------
// XFMultiHeadAttention: B=4, S=2048, D=1024, H=16, depth=64.
// I/O: float32 (per reference). Internal compute: bf16 MFMA, f32 accum.
// transpose W (reused 2MB buf) -> QKV GEMMs -> flash attention -> out GEMM.
// ws (18MB): WT(2MB) + Qh(16MB, reused as ctx).  Kh,Vt live in d_out (32MB),
// dead before the final GEMM overwrites d_out with f32 output.
// ---------------------------------------------------------------------------

#define S_LEN 2048
#define NHEAD 16
#define DEPTH 64
#define DMODEL 1024

typedef __bf16 bf16x8 __attribute__((ext_vector_type(8)));
typedef float f32x4 __attribute__((ext_vector_type(4)));
typedef uint16_t u16x8 __attribute__((ext_vector_type(8)));

__device__ __forceinline__ float bf2f(uint16_t u) {
    union { uint32_t i; float f; } v; v.i = ((uint32_t)u) << 16; return v.f;
}
__device__ __forceinline__ uint16_t f2bf(float x) {
    __hip_bfloat16 h = __float2bfloat16(x);  // RNE
    union { __hip_bfloat16 h; uint16_t u; } v; v.h = h; return v.u;
}
__device__ __forceinline__ u16x8 cvt8(const float* p) {
    u16x8 r;
#pragma unroll
    for (int i = 0; i < 8; ++i) r[i] = f2bf(p[i]);
    return r;
}

// ---------------------------------------------------------------------------
// Weight transpose + bf16 cast: WT[n][k] = bf16(W[k][n]), 1024x1024
// ---------------------------------------------------------------------------
__global__ void transpose1(const float* __restrict__ src, uint16_t* __restrict__ dst) {
    __shared__ uint16_t tile[32][33];
    int bx = blockIdx.x * 32, by = blockIdx.y * 32;
    int x = threadIdx.x, y0 = threadIdx.y;
#pragma unroll
    for (int i = 0; i < 4; ++i) {
        int y = y0 + i * 8;
        tile[y][x] = f2bf(src[(size_t)(by + y) * DMODEL + bx + x]);
    }
    __syncthreads();
#pragma unroll
    for (int i = 0; i < 4; ++i) {
        int y = y0 + i * 8;
        dst[(size_t)(bx + y) * DMODEL + by + x] = tile[x][y];
    }
}

// ---------------------------------------------------------------------------
// NT GEMM: out = X @ WT^T + bias.  128x128 tile, BK=32, 4 waves, 256 thr.
// in_mode  0: X f32 row-major [8192,1024] (converted to bf16 in staging)
// in_mode  1: X bf16 head-split [B,H,S,64]; row=(b*2048+s), col=h*64+dp
// out_mode 0: float out[row*1024+col]          (final output)
// out_mode 1: bf16  out[((b*16+h)*2048+s)*64+dp]   ([B,H,S,64])
// out_mode 2: bf16  out[((b*16+h)*64+dp)*2048+s]   ([B,H,64,S] = V^T)
// ---------------------------------------------------------------------------
__global__ __launch_bounds__(256, 2)
void gemm_bt(const void* __restrict__ Xv, const uint16_t* __restrict__ Wt,
             const float* __restrict__ bias, void* __restrict__ outv,
             int K, int in_mode, int out_mode) {
    __shared__ __align__(16) uint16_t As[128 * 32];
    __shared__ __align__(16) uint16_t Bs[128 * 32];

    const int t = threadIdx.x;
    const int lane = t & 63, quad = lane >> 4, l16 = lane & 15;
    const int w = t >> 6, wm = w >> 1, wn = w & 1;
    const int m0 = blockIdx.y * 128, n0 = blockIdx.x * 128;

    // staging: thread t covers tile row (t>>1), cols scol..scol+15
    const int srow = t >> 1;
    const int scol = (t & 1) * 16;

    f32x4 acc[4][4];
    const f32x4 z4 = {0.f, 0.f, 0.f, 0.f};
#pragma unroll
    for (int mt = 0; mt < 4; ++mt)
#pragma unroll
        for (int nt = 0; nt < 4; ++nt) acc[mt][nt] = z4;

    for (int kc = 0; kc < K; kc += 32) {
        u16x8 a0, a1;
        if (in_mode == 0) {
            const float* pa = (const float*)Xv + (size_t)(m0 + srow) * K + kc + scol;
            a0 = cvt8(pa);
            a1 = cvt8(pa + 8);
        } else {
            int row = m0 + srow;
            int b_ = row >> 11, s_ = row & 2047;
            int col = kc + scol;               // col..col+15 within one 64-block
            int h_ = col >> 6, dp = col & 63;
            const uint16_t* pa = (const uint16_t*)Xv
                + (((size_t)(b_ * NHEAD + h_)) * S_LEN + s_) * DEPTH + dp;
            a0 = *(const u16x8*)pa;
            a1 = *(const u16x8*)(pa + 8);
        }
        const uint16_t* pb = Wt + (size_t)(n0 + srow) * K + kc + scol;
        u16x8 b0 = *(const u16x8*)pb;
        u16x8 b1 = *(const u16x8*)(pb + 8);

        *(u16x8*)&As[srow * 32 + scol]     = a0;
        *(u16x8*)&As[srow * 32 + scol + 8] = a1;
        *(u16x8*)&Bs[srow * 32 + scol]     = b0;
        *(u16x8*)&Bs[srow * 32 + scol + 8] = b1;
        __syncthreads();

        bf16x8 af[4], bfr[4];
#pragma unroll
        for (int mt = 0; mt < 4; ++mt)
            af[mt] = *(const bf16x8*)&As[(wm * 64 + mt * 16 + l16) * 32 + quad * 8];
#pragma unroll
        for (int nt = 0; nt < 4; ++nt)
            bfr[nt] = *(const bf16x8*)&Bs[(wn * 64 + nt * 16 + l16) * 32 + quad * 8];
#pragma unroll
        for (int mt = 0; mt < 4; ++mt)
#pragma unroll
            for (int nt = 0; nt < 4; ++nt)
                acc[mt][nt] = __builtin_amdgcn_mfma_f32_16x16x32_bf16(af[mt], bfr[nt],
                                                                      acc[mt][nt], 0, 0, 0);
        __syncthreads();
    }

    // epilogue: C/D layout col=lane&15, row=quad*4+reg
#pragma unroll
    for (int nt = 0; nt < 4; ++nt) {
        int col = n0 + wn * 64 + nt * 16 + l16;
        float bval = bias[col];
        int h = col >> 6, dp = col & 63;
#pragma unroll
        for (int mt = 0; mt < 4; ++mt) {
#pragma unroll
            for (int r = 0; r < 4; ++r) {
                int row = m0 + wm * 64 + mt * 16 + quad * 4 + r;
                float val = acc[mt][nt][r] + bval;
                if (out_mode == 0) {
                    ((float*)outv)[(size_t)row * DMODEL + col] = val;
                } else if (out_mode == 1) {
                    int b = row >> 11, s = row & 2047;
                    ((uint16_t*)outv)[(((size_t)(b * NHEAD + h)) * S_LEN + s) * DEPTH + dp] = f2bf(val);
                } else {
                    int b = row >> 11, s = row & 2047;
                    ((uint16_t*)outv)[(((size_t)(b * NHEAD + h)) * DEPTH + dp) * S_LEN + s] = f2bf(val);
                }
            }
        }
    }
}

// ---------------------------------------------------------------------------
// Flash attention. Grid (16 q-tiles, 64 head-batches). 256 thr (4 waves).
// Q-tile = 128 rows (32/wave), K/V tiles of 64 keys. Online softmax.
// Qh,Kh: bf16 [BH][S][64]  Vt: bf16 [BH][64][S]  mask: f32 [B][S] (1=masked)
// ctx: bf16 head-split [BH][S][64] — aliases Qh (each block reads only its own
// Q rows into registers before later overwriting exactly those rows).
// ---------------------------------------------------------------------------
__global__ __launch_bounds__(256, 2)
void flash_attn(const uint16_t* __restrict__ Qh, const uint16_t* __restrict__ Kh,
                const uint16_t* __restrict__ Vt, const float* __restrict__ mask,
                uint16_t* __restrict__ ctx) {
    // stride 72 (=144B): 16B-aligned rows, max 2-way bank alias (free)
    __shared__ __align__(16) uint16_t Ks[64 * 72];
    __shared__ __align__(16) uint16_t Vs[64 * 72];
    __shared__ __align__(16) uint16_t Ps[4][32 * 72];

    const int t = threadIdx.x;
    const int w = t >> 6, lane = t & 63, quad = lane >> 4, l16 = lane & 15;
    const int bh = blockIdx.y, b = bh >> 4;
    const int q0 = blockIdx.x * 128;

    // Q fragments (A-operand: A[m=l16][k=quad*8+j]) stay in registers
    bf16x8 aq[2][2];
#pragma unroll
    for (int mt = 0; mt < 2; ++mt)
#pragma unroll
        for (int kc = 0; kc < 2; ++kc)
            aq[mt][kc] = *(const bf16x8*)(Qh + ((size_t)bh * S_LEN + q0 + w * 32 + mt * 16 + l16) * DEPTH
                                          + kc * 32 + quad * 8);

    float mrow[2][4], lrow[2][4];
    f32x4 Oacc[2][4];
    const f32x4 z4 = {0.f, 0.f, 0.f, 0.f};
#pragma unroll
    for (int mt = 0; mt < 2; ++mt)
#pragma unroll
        for (int r = 0; r < 4; ++r) { mrow[mt][r] = -1e30f; lrow[mt][r] = 0.f; }
#pragma unroll
    for (int mt = 0; mt < 2; ++mt)
#pragma unroll
        for (int nt = 0; nt < 4; ++nt) Oacc[mt][nt] = z4;

    const int vrow = t >> 3, vc = (t & 7) * 8;  // staging: 64 rows x 64 cols

    for (int kt = 0; kt < 32; ++kt) {
        const int k0 = kt * 64;
#pragma unroll
        for (int i = 0; i < 2; ++i) {
            int row = vrow + i * 32;
            u16x8 kv = *(const u16x8*)(Kh + ((size_t)bh * S_LEN + k0 + row) * DEPTH + vc);
            *(u16x8*)&Ks[row * 72 + vc] = kv;
            u16x8 vv = *(const u16x8*)(Vt + ((size_t)bh * DEPTH + row) * S_LEN + k0 + vc);
            *(u16x8*)&Vs[row * 72 + vc] = vv;
        }
        __syncthreads();

        float pen[4];
#pragma unroll
        for (int nt = 0; nt < 4; ++nt)
            pen[nt] = -1e9f * mask[b * S_LEN + k0 + nt * 16 + l16];

        // S = Q @ K^T
        f32x4 sacc[2][4];
#pragma unroll
        for (int mt = 0; mt < 2; ++mt)
#pragma unroll
            for (int nt = 0; nt < 4; ++nt) sacc[mt][nt] = z4;
#pragma unroll
        for (int kc = 0; kc < 2; ++kc) {
#pragma unroll
            for (int nt = 0; nt < 4; ++nt) {
                bf16x8 bk = *(const bf16x8*)&Ks[(nt * 16 + l16) * 72 + kc * 32 + quad * 8];
#pragma unroll
                for (int mt = 0; mt < 2; ++mt)
                    sacc[mt][nt] = __builtin_amdgcn_mfma_f32_16x16x32_bf16(aq[mt][kc], bk,
                                                                           sacc[mt][nt], 0, 0, 0);
            }
        }

        // online softmax per row (row = quad*4+r within each 16-row m-tile)
#pragma unroll
        for (int mt = 0; mt < 2; ++mt) {
#pragma unroll
            for (int r = 0; r < 4; ++r) {
                float s0 = sacc[mt][0][r] * 0.125f + pen[0];
                float s1 = sacc[mt][1][r] * 0.125f + pen[1];
                float s2 = sacc[mt][2][r] * 0.125f + pen[2];
                float s3 = sacc[mt][3][r] * 0.125f + pen[3];
                float rmax = fmaxf(fmaxf(s0, s1), fmaxf(s2, s3));
                rmax = fmaxf(rmax, __shfl_xor(rmax, 1));
                rmax = fmaxf(rmax, __shfl_xor(rmax, 2));
                rmax = fmaxf(rmax, __shfl_xor(rmax, 4));
                rmax = fmaxf(rmax, __shfl_xor(rmax, 8));
                float mnew = fmaxf(mrow[mt][r], rmax);
                float alpha = __expf(mrow[mt][r] - mnew);
                mrow[mt][r] = mnew;
                float p0 = __expf(s0 - mnew);
                float p1 = __expf(s1 - mnew);
                float p2 = __expf(s2 - mnew);
                float p3 = __expf(s3 - mnew);
                float rs = (p0 + p1) + (p2 + p3);
                rs += __shfl_xor(rs, 1);
                rs += __shfl_xor(rs, 2);
                rs += __shfl_xor(rs, 4);
                rs += __shfl_xor(rs, 8);
                lrow[mt][r] = lrow[mt][r] * alpha + rs;
#pragma unroll
                for (int nt = 0; nt < 4; ++nt) Oacc[mt][nt][r] *= alpha;
                int prow = mt * 16 + quad * 4 + r;
                Ps[w][prow * 72 + 0 * 16 + l16] = f2bf(p0);
                Ps[w][prow * 72 + 1 * 16 + l16] = f2bf(p1);
                Ps[w][prow * 72 + 2 * 16 + l16] = f2bf(p2);
                Ps[w][prow * 72 + 3 * 16 + l16] = f2bf(p3);
            }
        }
        __syncthreads();  // Ps visibility (conservative)

        // O += P @ V   (A = P from LDS, B = V^T rows = contiguous keys)
#pragma unroll
        for (int kc = 0; kc < 2; ++kc) {
#pragma unroll
            for (int mt = 0; mt < 2; ++mt) {
                bf16x8 ap = *(const bf16x8*)&Ps[w][(mt * 16 + l16) * 72 + kc * 32 + quad * 8];
#pragma unroll
                for (int nt = 0; nt < 4; ++nt) {
                    bf16x8 bv = *(const bf16x8*)&Vs[(nt * 16 + l16) * 72 + kc * 32 + quad * 8];
                    Oacc[mt][nt] = __builtin_amdgcn_mfma_f32_16x16x32_bf16(ap, bv,
                                                                           Oacc[mt][nt], 0, 0, 0);
                }
            }
        }
        __syncthreads();  // before next staging overwrites Ks/Vs
    }

    // epilogue: ctx (head-split bf16, aliases Qh) = O / l
#pragma unroll
    for (int mt = 0; mt < 2; ++mt) {
#pragma unroll
        for (int r = 0; r < 4; ++r) {
            float inv = 1.0f / lrow[mt][r];
            int srow = q0 + w * 32 + mt * 16 + quad * 4 + r;
            size_t base = ((size_t)bh * S_LEN + srow) * DEPTH;
#pragma unroll
            for (int nt = 0; nt < 4; ++nt)
                ctx[base + nt * 16 + l16] = f2bf(Oacc[mt][nt][r] * inv);
        }
    }
}

// ---------------------------------------------------------------------------
extern "C" void kernel_launch(void* const* d_in, const int* in_sizes, int n_in,
                              void* d_out, int out_size, void* d_ws, size_t ws_size,
                              hipStream_t stream) {
    const float* v    = (const float*)d_in[0];
    const float* k    = (const float*)d_in[1];
    const float* q    = (const float*)d_in[2];
    const float* mask = (const float*)d_in[3];
    const float* Wq   = (const float*)d_in[4];
    const float* bq   = (const float*)d_in[5];
    const float* Wk   = (const float*)d_in[6];
    const float* bk   = (const float*)d_in[7];
    const float* Wv   = (const float*)d_in[8];
    const float* bv   = (const float*)d_in[9];
    const float* Wo   = (const float*)d_in[10];
    const float* bo   = (const float*)d_in[11];
    float* out = (float*)d_out;

    // ws: WT(2MB bf16) + Qh/ctx(16MB bf16) = 18MB (ws >= 32MB confirmed r4)
    uint16_t* WT = (uint16_t*)d_ws;
    uint16_t* Qh = (uint16_t*)((char*)d_ws + (size_t)DMODEL * DMODEL * 2);
    // Kh, Vt (16MB bf16 each) in d_out (32MB f32) — dead before final GEMM
    uint16_t* Kh = (uint16_t*)d_out;
    uint16_t* Vt = (uint16_t*)d_out + (size_t)64 * S_LEN * DEPTH;
    uint16_t* ctx = Qh;  // flash reads only its own Q rows before writing them

    dim3 tgrid(32, 32), tblk(32, 8);
    dim3 ggrid(8, 64), gblk(256);

    transpose1<<<tgrid, tblk, 0, stream>>>(Wq, WT);
    gemm_bt<<<ggrid, gblk, 0, stream>>>(q, WT, bq, Qh, DMODEL, 0, 1);
    transpose1<<<tgrid, tblk, 0, stream>>>(Wk, WT);
    gemm_bt<<<ggrid, gblk, 0, stream>>>(k, WT, bk, Kh, DMODEL, 0, 1);
    transpose1<<<tgrid, tblk, 0, stream>>>(Wv, WT);
    gemm_bt<<<ggrid, gblk, 0, stream>>>(v, WT, bv, Vt, DMODEL, 0, 2);

    flash_attn<<<dim3(16, 64), 256, 0, stream>>>(Qh, Kh, Vt, mask, ctx);

    transpose1<<<tgrid, tblk, 0, stream>>>(Wo, WT);
    gemm_bt<<<ggrid, gblk, 0, stream>>>(ctx, WT, bo, out, DMODEL, 1, 0);
}

// Round 6
// 468.871 us; speedup vs baseline: 1.2664x; 1.2664x over previous
//
#include <hip/hip_runtime.h>
#include <hip/hip_bf16.h>
#include <stdint.h>

// ---------------------------------------------------------------------------
// XFMultiHeadAttention: B=4, S=2048, D=1024, H=16, depth=64.
// I/O f32, compute bf16 MFMA. Pipeline:
//   scan(mask->scatter idx) ; transpose4(W) ;
//   Q GEMM -> Qh ; K GEMM -(compact scatter)-> Kc ; V GEMM -(scatter)-> Vc^T ;
//   flash(compacted keys, fixed-max softmax) -> ctx(=Qh) ; out GEMM -> d_out
// ws (24MB): WT4(8MB) + Qh/ctx(16MB) + scidx(32KB) + nb(16B).
// Kc,Vc live in d_out (32MB f32), dead before final GEMM writes output.
// Compaction is EXACT: masked keys get exp(s-1e9-m) == 0.0f in fp32.
// ---------------------------------------------------------------------------

#define S_LEN 2048
#define NHEAD 16
#define DEPTH 64
#define DMODEL 1024

typedef __bf16 bf16x8 __attribute__((ext_vector_type(8)));
typedef float f32x4 __attribute__((ext_vector_type(4)));
typedef uint16_t u16x8 __attribute__((ext_vector_type(8)));

__device__ __forceinline__ uint16_t f2bf(float x) {
    __hip_bfloat16 h = __float2bfloat16(x);  // RNE
    union { __hip_bfloat16 h; uint16_t u; } v; v.h = h; return v.u;
}
__device__ __forceinline__ u16x8 cvt8(const float* p) {
    f32x4 lo = *(const f32x4*)p, hi = *(const f32x4*)(p + 4);
    u16x8 r;
#pragma unroll
    for (int i = 0; i < 4; ++i) { r[i] = f2bf(lo[i]); r[i + 4] = f2bf(hi[i]); }
    return r;
}
// async 16B global->LDS (dest = wave-uniform base + lane*16)  [m97 pattern]
__device__ __forceinline__ void async16(const void* g, void* l) {
    __builtin_amdgcn_global_load_lds((__attribute__((address_space(1))) void*)(g),
                                     (__attribute__((address_space(3))) void*)(l),
                                     16, 0, 0);
}

// ---------------------------------------------------------------------------
// Mask scan: per batch, scidx[s] = compacted index if unmasked else -1; nb[b].
// 4 blocks x 256 thr; each thread handles 8 positions.
// ---------------------------------------------------------------------------
__global__ void mask_scan(const float* __restrict__ mask, int* __restrict__ scidx,
                          int* __restrict__ nb) {
    __shared__ int part[256];
    const int b = blockIdx.x, tid = threadIdx.x;
    int flags[8], cnt = 0;
#pragma unroll
    for (int i = 0; i < 8; ++i) {
        flags[i] = (mask[b * S_LEN + tid * 8 + i] == 0.0f) ? 1 : 0;
        cnt += flags[i];
    }
    part[tid] = cnt;
    __syncthreads();
    // Hillis-Steele inclusive scan over 256
    for (int st = 1; st < 256; st <<= 1) {
        int v = (tid >= st) ? part[tid - st] : 0;
        __syncthreads();
        part[tid] += v;
        __syncthreads();
    }
    int run = part[tid] - cnt;  // exclusive offset
#pragma unroll
    for (int i = 0; i < 8; ++i) {
        scidx[b * S_LEN + tid * 8 + i] = flags[i] ? run : -1;
        run += flags[i];
    }
    if (tid == 255) nb[b] = part[255];
}

// ---------------------------------------------------------------------------
// Weight transpose + bf16 cast: WT4[z][n][k] = bf16(W_z[k][n]); z=Wq,Wk,Wv,Wo
// ---------------------------------------------------------------------------
__global__ void transpose4(const float* __restrict__ w0, const float* __restrict__ w1,
                           const float* __restrict__ w2, const float* __restrict__ w3,
                           uint16_t* __restrict__ dst) {
    __shared__ uint16_t tile[32][33];
    const float* src = (blockIdx.z == 0) ? w0 : (blockIdx.z == 1) ? w1
                     : (blockIdx.z == 2) ? w2 : w3;
    uint16_t* d = dst + (size_t)blockIdx.z * DMODEL * DMODEL;
    int bx = blockIdx.x * 32, by = blockIdx.y * 32;
    int x = threadIdx.x, y0 = threadIdx.y;
#pragma unroll
    for (int i = 0; i < 4; ++i) {
        int y = y0 + i * 8;
        tile[y][x] = f2bf(src[(size_t)(by + y) * DMODEL + bx + x]);
    }
    __syncthreads();
#pragma unroll
    for (int i = 0; i < 4; ++i) {
        int y = y0 + i * 8;
        d[(size_t)(bx + y) * DMODEL + by + x] = tile[x][y];
    }
}

// ---------------------------------------------------------------------------
// NT GEMM: out = X @ WT^T + bias.  128x128 tile, BK=32, 4 waves, 256 thr.
// in_mode  0: X f32 row-major [8192,1024] (VGPR cvt staging; B via async16)
// in_mode  1: X bf16 head-split [B,H,S,64] (A and B via async16)
// out_mode 0: f32  out[row*1024+col]
// out_mode 1: bf16 out[((b*16+h)*2048+s)*64+dp]          (head-split)
// out_mode 3: bf16 Kc[((b*16+h)*2048+s')*64+dp], s'=scidx (compact scatter)
// out_mode 4: bf16 Vc[((b*16+h)*64+dp)*2048+s'], s'=scidx (compact V^T)
// ---------------------------------------------------------------------------
__global__ __launch_bounds__(256, 2)
void gemm_bt(const void* __restrict__ Xv, const uint16_t* __restrict__ Wt,
             const float* __restrict__ bias, void* __restrict__ outv,
             const int* __restrict__ scidx, int in_mode, int out_mode) {
    __shared__ __align__(16) uint16_t As[128 * 32];
    __shared__ __align__(16) uint16_t Bs[128 * 32];

    const int t = threadIdx.x;
    const int lane = t & 63, quad = lane >> 4, l16 = lane & 15;
    const int w = t >> 6, wm = w >> 1, wn = w & 1;
    const int m0 = blockIdx.y * 128, n0 = blockIdx.x * 128;
    const int K = DMODEL;

    const int r_ld = lane >> 2;        // row within 16-row chunk (async path)
    const int c_ld = (lane & 3) * 8;   // 8-col group
    const uint16_t* gB = Wt + (size_t)(n0 + r_ld) * K + c_ld;

    // VGPR staging coords (f32 A path): thread t -> row t>>1, cols (t&1)*16..+15
    const int srow = t >> 1, scol = (t & 1) * 16;

    f32x4 acc[4][4];
    const f32x4 z4 = {0.f, 0.f, 0.f, 0.f};
#pragma unroll
    for (int mt = 0; mt < 4; ++mt)
#pragma unroll
        for (int nt = 0; nt < 4; ++nt) acc[mt][nt] = z4;

    for (int kc = 0; kc < K; kc += 32) {
#pragma unroll
        for (int i = 0; i < 2; ++i) {
            int c = w * 2 + i;  // chunk 0..7 = rows 16c..16c+15
            async16(gB + (size_t)(c * 16) * K + kc, &Bs[c * 512]);
        }
        if (in_mode == 0) {
            const float* pa = (const float*)Xv + (size_t)(m0 + srow) * K + kc + scol;
            *(u16x8*)&As[srow * 32 + scol]     = cvt8(pa);
            *(u16x8*)&As[srow * 32 + scol + 8] = cvt8(pa + 8);
        } else {
            // bf16 head-split: rows stride 64, 32-col chunk stays in one head
            int h_ = kc >> 6, dpb = kc & 63;
#pragma unroll
            for (int i = 0; i < 2; ++i) {
                int c = w * 2 + i;
                int row = m0 + c * 16 + r_ld;
                int b_ = row >> 11, s_ = row & 2047;
                async16((const uint16_t*)Xv
                        + (((size_t)(b_ * NHEAD + h_)) * S_LEN + s_) * DEPTH + dpb + c_ld,
                        &As[c * 512]);
            }
        }
        __syncthreads();

        bf16x8 af[4], bfr[4];
#pragma unroll
        for (int mt = 0; mt < 4; ++mt)
            af[mt] = *(const bf16x8*)&As[(wm * 64 + mt * 16 + l16) * 32 + quad * 8];
#pragma unroll
        for (int nt = 0; nt < 4; ++nt)
            bfr[nt] = *(const bf16x8*)&Bs[(wn * 64 + nt * 16 + l16) * 32 + quad * 8];
#pragma unroll
        for (int mt = 0; mt < 4; ++mt)
#pragma unroll
            for (int nt = 0; nt < 4; ++nt)
                acc[mt][nt] = __builtin_amdgcn_mfma_f32_16x16x32_bf16(af[mt], bfr[nt],
                                                                      acc[mt][nt], 0, 0, 0);
        __syncthreads();
    }

    // epilogue: C/D layout col=lane&15, row=quad*4+reg
#pragma unroll
    for (int nt = 0; nt < 4; ++nt) {
        int col = n0 + wn * 64 + nt * 16 + l16;
        float bval = bias[col];
        int h = col >> 6, dp = col & 63;
#pragma unroll
        for (int mt = 0; mt < 4; ++mt) {
#pragma unroll
            for (int r = 0; r < 4; ++r) {
                int row = m0 + wm * 64 + mt * 16 + quad * 4 + r;
                float val = acc[mt][nt][r] + bval;
                int b = row >> 11, s = row & 2047;
                if (out_mode == 0) {
                    ((float*)outv)[(size_t)row * DMODEL + col] = val;
                } else if (out_mode == 1) {
                    ((uint16_t*)outv)[(((size_t)(b * NHEAD + h)) * S_LEN + s) * DEPTH + dp] = f2bf(val);
                } else if (out_mode == 3) {
                    int sp = scidx[b * S_LEN + s];
                    if (sp >= 0)
                        ((uint16_t*)outv)[(((size_t)(b * NHEAD + h)) * S_LEN + sp) * DEPTH + dp] = f2bf(val);
                } else {
                    int sp = scidx[b * S_LEN + s];
                    if (sp >= 0)
                        ((uint16_t*)outv)[(((size_t)(b * NHEAD + h)) * DEPTH + dp) * S_LEN + sp] = f2bf(val);
                }
            }
        }
    }
}

// ---------------------------------------------------------------------------
// Flash attention over COMPACTED keys, fixed-max softmax (m=12, exp2-domain).
// Grid (16 q-tiles, 64 bh). 256 thr (4 waves), 32 q-rows/wave.
// Qh: bf16 [BH][S][64]  Kc: bf16 [BH][S][64] (first nb[b] rows valid)
// Vc: bf16 [BH][64][S] (first nb[b] cols valid)  ctx(=Qh): bf16 [BH][S][64]
// ---------------------------------------------------------------------------
__global__ __launch_bounds__(256, 2)
void flash_attn(const uint16_t* __restrict__ Qh, const uint16_t* __restrict__ Kc,
                const uint16_t* __restrict__ Vc, const int* __restrict__ nb,
                uint16_t* __restrict__ ctx) {
    __shared__ __align__(16) uint16_t Ks[64 * 72];
    __shared__ __align__(16) uint16_t Vs[64 * 72];
    __shared__ __align__(16) uint16_t Ps[4][32 * 72];

    const int t = threadIdx.x;
    const int w = t >> 6, lane = t & 63, quad = lane >> 4, l16 = lane & 15;
    const int bh = blockIdx.y, b = bh >> 4;
    const int q0 = blockIdx.x * 128;
    const int nbv = nb[b];
    const int ntiles = (nbv + 63) >> 6;

    // Q fragments (A-operand: A[m=l16][k=quad*8+j]) in registers for whole loop
    bf16x8 aq[2][2];
#pragma unroll
    for (int mt = 0; mt < 2; ++mt)
#pragma unroll
        for (int kc = 0; kc < 2; ++kc)
            aq[mt][kc] = *(const bf16x8*)(Qh + ((size_t)bh * S_LEN + q0 + w * 32 + mt * 16 + l16) * DEPTH
                                          + kc * 32 + quad * 8);

    float lrow[2][4];
    f32x4 Oacc[2][4];
    const f32x4 z4 = {0.f, 0.f, 0.f, 0.f};
#pragma unroll
    for (int mt = 0; mt < 2; ++mt)
#pragma unroll
        for (int r = 0; r < 4; ++r) lrow[mt][r] = 0.f;
#pragma unroll
    for (int mt = 0; mt < 2; ++mt)
#pragma unroll
        for (int nt = 0; nt < 4; ++nt) Oacc[mt][nt] = z4;

    // fixed-max exp2-domain softmax: p = exp2(s*C2 - M2); C2=0.125*log2e, M2=12*log2e
    const float C2 = 0.18033688f;
    const float M2 = 17.312340f;

    const int vrow = t >> 3, vc = (t & 7) * 8;  // staging 64x64, 2 passes

    for (int kt = 0; kt < ntiles; ++kt) {
        const int k0 = kt * 64;
#pragma unroll
        for (int i = 0; i < 2; ++i) {
            int row = vrow + i * 32;
            // zero-pad beyond nbv (poison-garbage firewall; P=0 there anyway)
            u16x8 kv = *(const u16x8*)(Kc + ((size_t)bh * S_LEN + k0 + row) * DEPTH + vc);
            u16x8 vv = *(const u16x8*)(Vc + ((size_t)bh * DEPTH + row) * S_LEN + k0 + vc);
            if (k0 + row >= nbv) { kv = (u16x8)(uint16_t)0; }
            *(u16x8*)&Ks[row * 72 + vc] = kv;
            *(u16x8*)&Vs[row * 72 + vc] = vv;
        }
        __syncthreads();

        float pen[4];
#pragma unroll
        for (int nt = 0; nt < 4; ++nt)
            pen[nt] = (k0 + nt * 16 + l16 < nbv) ? -M2 : -2e9f;  // exp2(-2e9)=0

        // S = Q @ K^T
        f32x4 sacc[2][4];
#pragma unroll
        for (int mt = 0; mt < 2; ++mt)
#pragma unroll
            for (int nt = 0; nt < 4; ++nt) sacc[mt][nt] = z4;
#pragma unroll
        for (int kc = 0; kc < 2; ++kc) {
#pragma unroll
            for (int nt = 0; nt < 4; ++nt) {
                bf16x8 bk = *(const bf16x8*)&Ks[(nt * 16 + l16) * 72 + kc * 32 + quad * 8];
#pragma unroll
                for (int mt = 0; mt < 2; ++mt)
                    sacc[mt][nt] = __builtin_amdgcn_mfma_f32_16x16x32_bf16(aq[mt][kc], bk,
                                                                           sacc[mt][nt], 0, 0, 0);
            }
        }

        // fixed-max softmax: p = exp2(s*C2 + pen); row sum via 16-lane shfl
#pragma unroll
        for (int mt = 0; mt < 2; ++mt) {
#pragma unroll
            for (int r = 0; r < 4; ++r) {
                float p0 = __builtin_exp2f(fmaf(sacc[mt][0][r], C2, pen[0]));
                float p1 = __builtin_exp2f(fmaf(sacc[mt][1][r], C2, pen[1]));
                float p2 = __builtin_exp2f(fmaf(sacc[mt][2][r], C2, pen[2]));
                float p3 = __builtin_exp2f(fmaf(sacc[mt][3][r], C2, pen[3]));
                float rs = (p0 + p1) + (p2 + p3);
                rs += __shfl_xor(rs, 1);
                rs += __shfl_xor(rs, 2);
                rs += __shfl_xor(rs, 4);
                rs += __shfl_xor(rs, 8);
                lrow[mt][r] += rs;
                int prow = mt * 16 + quad * 4 + r;
                Ps[w][prow * 72 + 0 * 16 + l16] = f2bf(p0);
                Ps[w][prow * 72 + 1 * 16 + l16] = f2bf(p1);
                Ps[w][prow * 72 + 2 * 16 + l16] = f2bf(p2);
                Ps[w][prow * 72 + 3 * 16 + l16] = f2bf(p3);
            }
        }
        __syncthreads();

        // O += P @ V
#pragma unroll
        for (int kc = 0; kc < 2; ++kc) {
#pragma unroll
            for (int mt = 0; mt < 2; ++mt) {
                bf16x8 ap = *(const bf16x8*)&Ps[w][(mt * 16 + l16) * 72 + kc * 32 + quad * 8];
#pragma unroll
                for (int nt = 0; nt < 4; ++nt) {
                    bf16x8 bv = *(const bf16x8*)&Vs[(nt * 16 + l16) * 72 + kc * 32 + quad * 8];
                    Oacc[mt][nt] = __builtin_amdgcn_mfma_f32_16x16x32_bf16(ap, bv,
                                                                           Oacc[mt][nt], 0, 0, 0);
                }
            }
        }
        __syncthreads();
    }

    // epilogue: ctx (head-split bf16, aliases Qh) = O / l
#pragma unroll
    for (int mt = 0; mt < 2; ++mt) {
#pragma unroll
        for (int r = 0; r < 4; ++r) {
            float inv = 1.0f / lrow[mt][r];
            int srow = q0 + w * 32 + mt * 16 + quad * 4 + r;
            size_t base = ((size_t)bh * S_LEN + srow) * DEPTH;
#pragma unroll
            for (int nt = 0; nt < 4; ++nt)
                ctx[base + nt * 16 + l16] = f2bf(Oacc[mt][nt][r] * inv);
        }
    }
}

// ---------------------------------------------------------------------------
extern "C" void kernel_launch(void* const* d_in, const int* in_sizes, int n_in,
                              void* d_out, int out_size, void* d_ws, size_t ws_size,
                              hipStream_t stream) {
    const float* v    = (const float*)d_in[0];
    const float* k    = (const float*)d_in[1];
    const float* q    = (const float*)d_in[2];
    const float* mask = (const float*)d_in[3];
    const float* Wq   = (const float*)d_in[4];
    const float* bq   = (const float*)d_in[5];
    const float* Wk   = (const float*)d_in[6];
    const float* bk   = (const float*)d_in[7];
    const float* Wv   = (const float*)d_in[8];
    const float* bv   = (const float*)d_in[9];
    const float* Wo   = (const float*)d_in[10];
    const float* bo   = (const float*)d_in[11];

    // ws: WT4(8MB) + Qh(16MB) + scidx(32KB) + nb(16B) = ~24MB (ws>=32MB: r4)
    char* p = (char*)d_ws;
    uint16_t* WT4 = (uint16_t*)p; p += (size_t)4 * DMODEL * DMODEL * 2;
    uint16_t* Qh  = (uint16_t*)p; p += (size_t)64 * S_LEN * DEPTH * 2;
    int* scidx    = (int*)p;      p += (size_t)4 * S_LEN * 4;
    int* nb       = (int*)p;      p += 16;

    uint16_t* WqT = WT4;
    uint16_t* WkT = WT4 + (size_t)1 * DMODEL * DMODEL;
    uint16_t* WvT = WT4 + (size_t)2 * DMODEL * DMODEL;
    uint16_t* WoT = WT4 + (size_t)3 * DMODEL * DMODEL;

    // Kc, Vc (16MB bf16 each) in d_out — dead before final GEMM writes f32 out
    uint16_t* Kc = (uint16_t*)d_out;
    uint16_t* Vc = (uint16_t*)d_out + (size_t)64 * S_LEN * DEPTH;
    uint16_t* ctx = Qh;  // flash reads only its own Q rows before writing them

    mask_scan<<<4, 256, 0, stream>>>(mask, scidx, nb);
    transpose4<<<dim3(32, 32, 4), dim3(32, 8), 0, stream>>>(Wq, Wk, Wv, Wo, WT4);

    dim3 ggrid(8, 64), gblk(256);
    gemm_bt<<<ggrid, gblk, 0, stream>>>(q, WqT, bq, Qh, scidx, 0, 1);
    gemm_bt<<<ggrid, gblk, 0, stream>>>(k, WkT, bk, Kc, scidx, 0, 3);
    gemm_bt<<<ggrid, gblk, 0, stream>>>(v, WvT, bv, Vc, scidx, 0, 4);

    flash_attn<<<dim3(16, 64), 256, 0, stream>>>(Qh, Kc, Vc, nb, ctx);

    gemm_bt<<<ggrid, gblk, 0, stream>>>(ctx, WoT, bo, (float*)d_out, scidx, 1, 0);
}